// Round 1
// baseline (2077.115 us; speedup 1.0000x reference)
//
#include <hip/hip_runtime.h>
#include <cstddef>

#define EPSV 0.1f
#define INV_EPS 10.0f
#define THRESHV 0.1f
#define MAX_ITER 100
// log(1/2048 + 1e-8)
#define LOG_MU_NU (-7.6245985f)

// ---- workspace layout (float offsets) ----
#define WS_U 0
#define WS_V 16384
#define WS_X2 32768
#define WS_Y2 49152
#define WS_ERR 65536
#define WS_DONE 65537  // stored as int in this slot

// ---- output layout (float offsets): dis[8][2048], cost[8], pi[8][2048][2048], C[8][2048][2048]
#define OUT_DIS 0
#define OUT_COST 16384
#define OUT_PI 16392ull
#define OUT_C 33570824ull

// ---------------- init: zero u, v, err, done, dis, cost ----------------
__global__ void k_init(float* __restrict__ ws, float* __restrict__ out) {
    int idx = blockIdx.x * 256 + threadIdx.x;
    if (idx < 16384) {
        ws[WS_U + idx] = 0.f;
        ws[WS_V + idx] = 0.f;
        out[OUT_DIS + idx] = 0.f;
    }
    if (idx < 8) out[OUT_COST + idx] = 0.f;
    if (idx == 0) {
        ws[WS_ERR] = 0.f;
        ((int*)ws)[WS_DONE] = 0;
    }
}

// ---------------- x2 / y2: mean of squares over D=64 ----------------
// 32768 rows total (x rows then y rows); 16 lanes per row via float4
__global__ __launch_bounds__(256) void k_sqnorm(const float* __restrict__ x,
                                                const float* __restrict__ y,
                                                float* __restrict__ ws) {
    int gid = blockIdx.x * 256 + threadIdx.x;
    int row = gid >> 4;
    int l = gid & 15;
    const float* src = (row < 16384) ? x : y;
    int r = row & 16383;
    float4 f = ((const float4*)(src + ((size_t)r << 6)))[l];
    float s = f.x * f.x + f.y * f.y + f.z * f.z + f.w * f.w;
    s += __shfl_xor(s, 1);
    s += __shfl_xor(s, 2);
    s += __shfl_xor(s, 4);
    s += __shfl_xor(s, 8);
    if (l == 0) ws[WS_X2 + row] = s * (1.0f / 64.0f);
}

// ---------------- C = x2_i + y2_j - (2/D) x.y^T ----------------
// 64x64 tile per workgroup, fp32 VALU (no fp32 MFMA on CDNA4)
__global__ __launch_bounds__(256) void k_gemm(const float* __restrict__ x,
                                              const float* __restrict__ y,
                                              const float* __restrict__ ws,
                                              float* __restrict__ out) {
    __shared__ float xsT[64][68];  // [k][i], padded to spread banks
    __shared__ float ysT[64][68];  // [k][j]
    int b = blockIdx.z;
    int i0 = blockIdx.y * 64, j0 = blockIdx.x * 64;
    int t = threadIdx.x;
    const float* xb = x + ((size_t)b << 17);
    const float* yb = y + ((size_t)b << 17);
#pragma unroll
    for (int l = 0; l < 4; ++l) {
        int idx = l * 256 + t;  // 0..1023
        int row = idx >> 4, kq = idx & 15;
        float4 fx = ((const float4*)(xb + ((size_t)(i0 + row) << 6)))[kq];
        xsT[kq * 4 + 0][row] = fx.x;
        xsT[kq * 4 + 1][row] = fx.y;
        xsT[kq * 4 + 2][row] = fx.z;
        xsT[kq * 4 + 3][row] = fx.w;
        float4 fy = ((const float4*)(yb + ((size_t)(j0 + row) << 6)))[kq];
        ysT[kq * 4 + 0][row] = fy.x;
        ysT[kq * 4 + 1][row] = fy.y;
        ysT[kq * 4 + 2][row] = fy.z;
        ysT[kq * 4 + 3][row] = fy.w;
    }
    __syncthreads();
    int tx = t & 15, ty = t >> 4;
    float acc[4][4] = {};
#pragma unroll 4
    for (int k = 0; k < 64; ++k) {
        float4 xa = *(const float4*)(&xsT[k][ty << 2]);
        float4 yv = *(const float4*)(&ysT[k][tx << 2]);
        float xr[4] = {xa.x, xa.y, xa.z, xa.w};
        float yc[4] = {yv.x, yv.y, yv.z, yv.w};
#pragma unroll
        for (int r = 0; r < 4; ++r)
#pragma unroll
            for (int c = 0; c < 4; ++c) acc[r][c] = fmaf(xr[r], yc[c], acc[r][c]);
    }
    const float* x2 = ws + WS_X2;
    const float* y2 = ws + WS_Y2;
    float x2r[4], y2c[4];
#pragma unroll
    for (int r = 0; r < 4; ++r) x2r[r] = x2[b * 2048 + i0 + ty * 4 + r];
#pragma unroll
    for (int c = 0; c < 4; ++c) y2c[c] = y2[b * 2048 + j0 + tx * 4 + c];
    float* C = out + OUT_C;
#pragma unroll
    for (int r = 0; r < 4; ++r) {
        int i = i0 + ty * 4 + r;
        float4 cv;
        cv.x = x2r[r] + y2c[0] - acc[r][0] * (2.0f / 64.0f);
        cv.y = x2r[r] + y2c[1] - acc[r][1] * (2.0f / 64.0f);
        cv.z = x2r[r] + y2c[2] - acc[r][2] * (2.0f / 64.0f);
        cv.w = x2r[r] + y2c[3] - acc[r][3] * (2.0f / 64.0f);
        *(float4*)(C + ((((size_t)b << 11) + i) << 11) + j0 + tx * 4) = cv;
    }
}

// ---------------- u update: one wave per row, two-pass LSE in registers ----------------
// u_new_i = eps*log_mu - eps*LSE_j((v_j - C_ij)/eps)   (u cancels algebraically)
__global__ __launch_bounds__(256) void k_urow(const float* __restrict__ out, float* __restrict__ ws) {
    const int* done = (const int*)ws + WS_DONE;
    if (*done) return;
    float* u = ws + WS_U;
    const float* v = ws + WS_V;
    float* err = ws + WS_ERR;
    const float* C = out + OUT_C;
    int gw = (blockIdx.x * 256 + threadIdx.x) >> 6;  // global wave id, 0..4095
    int lane = threadIdx.x & 63;
    for (int r = gw; r < 16384; r += 4096) {
        int b = r >> 11;
        const float4* Crow = (const float4*)(C + ((size_t)r << 11));
        const float4* vb = (const float4*)(v + (b << 11));
        float a[32];
        float m = -1e30f;
#pragma unroll
        for (int c = 0; c < 8; ++c) {
            float4 cf = Crow[(c << 6) + lane];
            float4 vf = vb[(c << 6) + lane];
            a[4 * c + 0] = (vf.x - cf.x) * INV_EPS;
            a[4 * c + 1] = (vf.y - cf.y) * INV_EPS;
            a[4 * c + 2] = (vf.z - cf.z) * INV_EPS;
            a[4 * c + 3] = (vf.w - cf.w) * INV_EPS;
            m = fmaxf(m, fmaxf(fmaxf(a[4 * c + 0], a[4 * c + 1]), fmaxf(a[4 * c + 2], a[4 * c + 3])));
        }
#pragma unroll
        for (int off = 1; off < 64; off <<= 1) m = fmaxf(m, __shfl_xor(m, off));
        float s = 0.f;
#pragma unroll
        for (int q = 0; q < 32; ++q) s += __expf(a[q] - m);
#pragma unroll
        for (int off = 1; off < 64; off <<= 1) s += __shfl_xor(s, off);
        if (lane == 0) {
            float lse = m + __logf(s);
            float unew = EPSV * (LOG_MU_NU - lse);
            atomicAdd(err, fabsf(unew - u[r]));
            u[r] = unew;
        }
    }
}

// ---------------- v update: streaming online-LSE down columns ----------------
// wg = 256 threads = 32 cols x 8 i-chunks; grid = 8*2048/32 = 512 wgs
__global__ __launch_bounds__(256) void k_vcol(const float* __restrict__ out, float* __restrict__ ws) {
    const int* done = (const int*)ws + WS_DONE;
    if (*done) return;
    const float* u = ws + WS_U;
    float* v = ws + WS_V;
    __shared__ float lm[8][32];
    __shared__ float ls[8][32];
    int b = blockIdx.x >> 6;
    int cg = blockIdx.x & 63;
    int j0 = cg * 32;
    int t = threadIdx.x;
    int jl = t & 31, chunk = t >> 5;
    const float* Cc = out + OUT_C + ((size_t)b << 22) + j0 + jl;
    const float* ub = u + (b << 11);
    float m = -1e30f, s = 0.f;
    int ibase = chunk << 8;
#pragma unroll 4
    for (int ii = 0; ii < 256; ++ii) {
        int i = ibase + ii;
        float xv = (ub[i] - Cc[(size_t)i << 11]) * INV_EPS;
        float nm = fmaxf(m, xv);
        s = s * __expf(m - nm) + __expf(xv - nm);
        m = nm;
    }
    lm[chunk][jl] = m;
    ls[chunk][jl] = s;
    __syncthreads();
    if (t < 32) {
        float M = -1e30f;
#pragma unroll
        for (int c = 0; c < 8; ++c) M = fmaxf(M, lm[c][t]);
        float S = 0.f;
#pragma unroll
        for (int c = 0; c < 8; ++c) S += ls[c][t] * __expf(lm[c][t] - M);
        float lse = M + __logf(S);
        v[(b << 11) + j0 + t] = EPSV * (LOG_MU_NU - lse);
    }
}

// ---------------- convergence check ----------------
__global__ void k_check(float* __restrict__ ws) {
    if (threadIdx.x == 0 && blockIdx.x == 0) {
        float e = ws[WS_ERR] * (1.0f / 8.0f);
        int* done = (int*)ws + WS_DONE;
        if (e < THRESHV) *done = 1;
        ws[WS_ERR] = 0.f;
    }
}

// ---------------- epilogue: pi, dis ----------------
// grid (8 jgroups, 16 ichunks, 8 batches), 256 threads; thread owns one column j
__global__ __launch_bounds__(256) void k_epi(float* __restrict__ out, const float* __restrict__ ws) {
    int b = blockIdx.z, jg = blockIdx.x, ic = blockIdx.y;
    int j = jg * 256 + threadIdx.x;
    int i0 = ic * 128;
    const float* u = ws + WS_U;
    const float* v = ws + WS_V;
    const float* C = out + OUT_C + ((size_t)b << 22);
    float* pi = out + OUT_PI + ((size_t)b << 22);
    float vj = v[(b << 11) + j];
    float accd = 0.f;
#pragma unroll 4
    for (int r = 0; r < 128; ++r) {
        int i = i0 + r;
        size_t idx = ((size_t)i << 11) + j;
        float cv = C[idx];
        float p = __expf((u[(b << 11) + i] + vj - cv) * INV_EPS);
        pi[idx] = p;
        accd = fmaf(p, cv, accd);
    }
    atomicAdd(out + OUT_DIS + (b << 11) + j, accd);
}

// ---------------- cost_b = sum_j dis_bj ----------------
__global__ void k_cost(float* __restrict__ out) {
    int b = blockIdx.x;
    float s = 0.f;
    for (int j = threadIdx.x; j < 2048; j += 256) s += out[OUT_DIS + (b << 11) + j];
#pragma unroll
    for (int off = 1; off < 64; off <<= 1) s += __shfl_xor(s, off);
    __shared__ float red[4];
    if ((threadIdx.x & 63) == 0) red[threadIdx.x >> 6] = s;
    __syncthreads();
    if (threadIdx.x == 0) out[OUT_COST + b] = red[0] + red[1] + red[2] + red[3];
}

extern "C" void kernel_launch(void* const* d_in, const int* in_sizes, int n_in,
                              void* d_out, int out_size, void* d_ws, size_t ws_size,
                              hipStream_t stream) {
    const float* x = (const float*)d_in[0];
    const float* y = (const float*)d_in[1];
    float* out = (float*)d_out;
    float* ws = (float*)d_ws;

    k_init<<<64, 256, 0, stream>>>(ws, out);
    k_sqnorm<<<2048, 256, 0, stream>>>(x, y, ws);
    k_gemm<<<dim3(32, 32, 8), 256, 0, stream>>>(x, y, ws, out);
    for (int it = 0; it < MAX_ITER; ++it) {
        k_urow<<<1024, 256, 0, stream>>>(out, ws);
        k_vcol<<<512, 256, 0, stream>>>(out, ws);
        k_check<<<1, 64, 0, stream>>>(ws);
    }
    k_epi<<<dim3(8, 16, 8), 256, 0, stream>>>(out, ws);
    k_cost<<<8, 256, 0, stream>>>(out);
}

// Round 2
// 1276.662 us; speedup vs baseline: 1.6270x; 1.6270x over previous
//
#include <hip/hip_runtime.h>
#include <cstddef>

#define EPSV 0.1f
#define INV_EPS 10.0f
#define THRESHV 0.1f
#define MAX_ITER 100
// log(1/2048 + 1e-8)
#define LOG_MU_NU (-7.6245985f)

typedef _Float16 half2_t __attribute__((ext_vector_type(2)));
typedef _Float16 half4_t __attribute__((ext_vector_type(4)));
typedef _Float16 half8_t __attribute__((ext_vector_type(8)));

// ---- workspace layout (float offsets) ----
#define WS_U 0
#define WS_V 16384
#define WS_X2 32768
#define WS_Y2 49152
#define WS_ERR 65536
#define WS_DONE 65537  // stored as int in this slot
// fp16 copy of C lives at byte offset WS_C16_BYTE (64-byte aligned)
#define WS_C16_BYTE 327680ull
#define C16_BYTES (33554432ull * 2ull)

// ---- output layout (float offsets): dis[8][2048], cost[8], pi[8][2048][2048], C[8][2048][2048]
#define OUT_DIS 0
#define OUT_COST 16384
#define OUT_PI 16392ull
#define OUT_C 33570824ull

// ---------------- init: zero u, v, err, done, dis, cost ----------------
__global__ void k_init(float* __restrict__ ws, float* __restrict__ out) {
    int idx = blockIdx.x * 256 + threadIdx.x;
    if (idx < 16384) {
        ws[WS_U + idx] = 0.f;
        ws[WS_V + idx] = 0.f;
        out[OUT_DIS + idx] = 0.f;
    }
    if (idx < 8) out[OUT_COST + idx] = 0.f;
    if (idx == 0) {
        ws[WS_ERR] = 0.f;
        ((int*)ws)[WS_DONE] = 0;
    }
}

// ---------------- x2 / y2: mean of squares over D=64 ----------------
__global__ __launch_bounds__(256) void k_sqnorm(const float* __restrict__ x,
                                                const float* __restrict__ y,
                                                float* __restrict__ ws) {
    int gid = blockIdx.x * 256 + threadIdx.x;
    int row = gid >> 4;
    int l = gid & 15;
    const float* src = (row < 16384) ? x : y;
    int r = row & 16383;
    float4 f = ((const float4*)(src + ((size_t)r << 6)))[l];
    float s = f.x * f.x + f.y * f.y + f.z * f.z + f.w * f.w;
    s += __shfl_xor(s, 1);
    s += __shfl_xor(s, 2);
    s += __shfl_xor(s, 4);
    s += __shfl_xor(s, 8);
    if (l == 0) ws[WS_X2 + row] = s * (1.0f / 64.0f);
}

// ---------------- C = x2_i + y2_j - (2/D) x.y^T  (+ optional fp16 copy) ----------------
__global__ __launch_bounds__(256) void k_gemm(const float* __restrict__ x,
                                              const float* __restrict__ y,
                                              const float* __restrict__ ws,
                                              float* __restrict__ out,
                                              _Float16* __restrict__ c16) {
    __shared__ float xsT[64][68];
    __shared__ float ysT[64][68];
    int b = blockIdx.z;
    int i0 = blockIdx.y * 64, j0 = blockIdx.x * 64;
    int t = threadIdx.x;
    const float* xb = x + ((size_t)b << 17);
    const float* yb = y + ((size_t)b << 17);
#pragma unroll
    for (int l = 0; l < 4; ++l) {
        int idx = l * 256 + t;
        int row = idx >> 4, kq = idx & 15;
        float4 fx = ((const float4*)(xb + ((size_t)(i0 + row) << 6)))[kq];
        xsT[kq * 4 + 0][row] = fx.x;
        xsT[kq * 4 + 1][row] = fx.y;
        xsT[kq * 4 + 2][row] = fx.z;
        xsT[kq * 4 + 3][row] = fx.w;
        float4 fy = ((const float4*)(yb + ((size_t)(j0 + row) << 6)))[kq];
        ysT[kq * 4 + 0][row] = fy.x;
        ysT[kq * 4 + 1][row] = fy.y;
        ysT[kq * 4 + 2][row] = fy.z;
        ysT[kq * 4 + 3][row] = fy.w;
    }
    __syncthreads();
    int tx = t & 15, ty = t >> 4;
    float acc[4][4] = {};
#pragma unroll 4
    for (int k = 0; k < 64; ++k) {
        float4 xa = *(const float4*)(&xsT[k][ty << 2]);
        float4 yv = *(const float4*)(&ysT[k][tx << 2]);
        float xr[4] = {xa.x, xa.y, xa.z, xa.w};
        float yc[4] = {yv.x, yv.y, yv.z, yv.w};
#pragma unroll
        for (int r = 0; r < 4; ++r)
#pragma unroll
            for (int c = 0; c < 4; ++c) acc[r][c] = fmaf(xr[r], yc[c], acc[r][c]);
    }
    const float* x2 = ws + WS_X2;
    const float* y2 = ws + WS_Y2;
    float x2r[4], y2c[4];
#pragma unroll
    for (int r = 0; r < 4; ++r) x2r[r] = x2[b * 2048 + i0 + ty * 4 + r];
#pragma unroll
    for (int c = 0; c < 4; ++c) y2c[c] = y2[b * 2048 + j0 + tx * 4 + c];
    float* C = out + OUT_C;
#pragma unroll
    for (int r = 0; r < 4; ++r) {
        int i = i0 + ty * 4 + r;
        float4 cv;
        cv.x = x2r[r] + y2c[0] - acc[r][0] * (2.0f / 64.0f);
        cv.y = x2r[r] + y2c[1] - acc[r][1] * (2.0f / 64.0f);
        cv.z = x2r[r] + y2c[2] - acc[r][2] * (2.0f / 64.0f);
        cv.w = x2r[r] + y2c[3] - acc[r][3] * (2.0f / 64.0f);
        size_t eoff = ((((size_t)b << 11) + i) << 11) + j0 + tx * 4;
        *(float4*)(C + eoff) = cv;
        if (c16) {
            half4_t h;
            h[0] = (_Float16)cv.x;
            h[1] = (_Float16)cv.y;
            h[2] = (_Float16)cv.z;
            h[3] = (_Float16)cv.w;
            *(half4_t*)(c16 + eoff) = h;
        }
    }
}

// ---------------- u update (fp16 C): one wave per row, two-pass LSE in registers ----------------
__global__ __launch_bounds__(256) void k_urow16(const _Float16* __restrict__ C16, float* __restrict__ ws) {
    const int* done = (const int*)ws + WS_DONE;
    if (*done) return;
    float* u = ws + WS_U;
    const float* v = ws + WS_V;
    float* err = ws + WS_ERR;
    int gw = (blockIdx.x * 256 + threadIdx.x) >> 6;
    int lane = threadIdx.x & 63;
    float eacc = 0.f;
    for (int r = gw; r < 16384; r += 4096) {
        int b = r >> 11;
        const half8_t* Crow = (const half8_t*)(C16 + ((size_t)r << 11));
        const float4* vb = (const float4*)(v + (b << 11));
        float a[32];
        float m = -1e30f;
#pragma unroll
        for (int c = 0; c < 4; ++c) {
            int base = (c << 6) + lane;
            half8_t ch = Crow[base];
            float4 vf0 = vb[2 * base];
            float4 vf1 = vb[2 * base + 1];
            float* ap = a + (c << 3);
            ap[0] = (vf0.x - (float)ch[0]) * INV_EPS;
            ap[1] = (vf0.y - (float)ch[1]) * INV_EPS;
            ap[2] = (vf0.z - (float)ch[2]) * INV_EPS;
            ap[3] = (vf0.w - (float)ch[3]) * INV_EPS;
            ap[4] = (vf1.x - (float)ch[4]) * INV_EPS;
            ap[5] = (vf1.y - (float)ch[5]) * INV_EPS;
            ap[6] = (vf1.z - (float)ch[6]) * INV_EPS;
            ap[7] = (vf1.w - (float)ch[7]) * INV_EPS;
#pragma unroll
            for (int q = 0; q < 8; ++q) m = fmaxf(m, ap[q]);
        }
#pragma unroll
        for (int off = 1; off < 64; off <<= 1) m = fmaxf(m, __shfl_xor(m, off));
        float s = 0.f;
#pragma unroll
        for (int q = 0; q < 32; ++q) s += __expf(a[q] - m);
#pragma unroll
        for (int off = 1; off < 64; off <<= 1) s += __shfl_xor(s, off);
        float unew = EPSV * (LOG_MU_NU - m - __logf(s));
        if (lane == 0) {
            eacc += fabsf(unew - u[r]);
            u[r] = unew;
        }
    }
    if (lane == 0) atomicAdd(err, eacc);
}

// ---------------- v update (fp16 C): streaming online-LSE down columns ----------------
// block = 256 thr = 16 col-pairs x 16 i-chunks(128 rows); grid = 8*2048/32 = 512
__global__ __launch_bounds__(256) void k_vcol16(const _Float16* __restrict__ C16, float* __restrict__ ws) {
    const int* done = (const int*)ws + WS_DONE;
    if (*done) return;
    const float* u = ws + WS_U;
    float* v = ws + WS_V;
    __shared__ float lm[16][33];
    __shared__ float ls[16][33];
    int b = blockIdx.x >> 6;
    int cg = blockIdx.x & 63;
    int j0 = cg * 32;
    int t = threadIdx.x;
    int jp = t & 15, chunk = t >> 4;
    const _Float16* Cc = C16 + ((size_t)b << 22) + j0 + jp * 2;
    const float* ub = u + (b << 11);
    float m0 = -1e30f, s0 = 0.f, m1 = -1e30f, s1 = 0.f;
    int ibase = chunk << 7;
#pragma unroll 4
    for (int ii = 0; ii < 128; ++ii) {
        int i = ibase + ii;
        half2_t ch = *(const half2_t*)(Cc + ((size_t)i << 11));
        float ui = ub[i];
        float x0 = (ui - (float)ch[0]) * INV_EPS;
        float x1 = (ui - (float)ch[1]) * INV_EPS;
        float nm0 = fmaxf(m0, x0);
        s0 = s0 * __expf(m0 - nm0) + __expf(x0 - nm0);
        m0 = nm0;
        float nm1 = fmaxf(m1, x1);
        s1 = s1 * __expf(m1 - nm1) + __expf(x1 - nm1);
        m1 = nm1;
    }
    lm[chunk][jp * 2] = m0;
    ls[chunk][jp * 2] = s0;
    lm[chunk][jp * 2 + 1] = m1;
    ls[chunk][jp * 2 + 1] = s1;
    __syncthreads();
    if (t < 32) {
        float M = -1e30f;
#pragma unroll
        for (int c = 0; c < 16; ++c) M = fmaxf(M, lm[c][t]);
        float S = 0.f;
#pragma unroll
        for (int c = 0; c < 16; ++c) S += ls[c][t] * __expf(lm[c][t] - M);
        v[(b << 11) + j0 + t] = EPSV * (LOG_MU_NU - M - __logf(S));
    }
}

// ---------------- fallback fp32 iteration kernels (small ws) ----------------
__global__ __launch_bounds__(256) void k_urow(const float* __restrict__ out, float* __restrict__ ws) {
    const int* done = (const int*)ws + WS_DONE;
    if (*done) return;
    float* u = ws + WS_U;
    const float* v = ws + WS_V;
    float* err = ws + WS_ERR;
    const float* C = out + OUT_C;
    int gw = (blockIdx.x * 256 + threadIdx.x) >> 6;
    int lane = threadIdx.x & 63;
    float eacc = 0.f;
    for (int r = gw; r < 16384; r += 4096) {
        int b = r >> 11;
        const float4* Crow = (const float4*)(C + ((size_t)r << 11));
        const float4* vb = (const float4*)(v + (b << 11));
        float a[32];
        float m = -1e30f;
#pragma unroll
        for (int c = 0; c < 8; ++c) {
            float4 cf = Crow[(c << 6) + lane];
            float4 vf = vb[(c << 6) + lane];
            a[4 * c + 0] = (vf.x - cf.x) * INV_EPS;
            a[4 * c + 1] = (vf.y - cf.y) * INV_EPS;
            a[4 * c + 2] = (vf.z - cf.z) * INV_EPS;
            a[4 * c + 3] = (vf.w - cf.w) * INV_EPS;
            m = fmaxf(m, fmaxf(fmaxf(a[4 * c + 0], a[4 * c + 1]), fmaxf(a[4 * c + 2], a[4 * c + 3])));
        }
#pragma unroll
        for (int off = 1; off < 64; off <<= 1) m = fmaxf(m, __shfl_xor(m, off));
        float s = 0.f;
#pragma unroll
        for (int q = 0; q < 32; ++q) s += __expf(a[q] - m);
#pragma unroll
        for (int off = 1; off < 64; off <<= 1) s += __shfl_xor(s, off);
        float unew = EPSV * (LOG_MU_NU - m - __logf(s));
        if (lane == 0) {
            eacc += fabsf(unew - u[r]);
            u[r] = unew;
        }
    }
    if (lane == 0) atomicAdd(err, eacc);
}

__global__ __launch_bounds__(256) void k_vcol(const float* __restrict__ out, float* __restrict__ ws) {
    const int* done = (const int*)ws + WS_DONE;
    if (*done) return;
    const float* u = ws + WS_U;
    float* v = ws + WS_V;
    __shared__ float lm[8][33];
    __shared__ float ls[8][33];
    int b = blockIdx.x >> 6;
    int cg = blockIdx.x & 63;
    int j0 = cg * 32;
    int t = threadIdx.x;
    int jl = t & 31, chunk = t >> 5;
    const float* Cc = out + OUT_C + ((size_t)b << 22) + j0 + jl;
    const float* ub = u + (b << 11);
    float m = -1e30f, s = 0.f;
    int ibase = chunk << 8;
#pragma unroll 4
    for (int ii = 0; ii < 256; ++ii) {
        int i = ibase + ii;
        float xv = (ub[i] - Cc[(size_t)i << 11]) * INV_EPS;
        float nm = fmaxf(m, xv);
        s = s * __expf(m - nm) + __expf(xv - nm);
        m = nm;
    }
    lm[chunk][jl] = m;
    ls[chunk][jl] = s;
    __syncthreads();
    if (t < 32) {
        float M = -1e30f;
#pragma unroll
        for (int c = 0; c < 8; ++c) M = fmaxf(M, lm[c][t]);
        float S = 0.f;
#pragma unroll
        for (int c = 0; c < 8; ++c) S += ls[c][t] * __expf(lm[c][t] - M);
        v[(b << 11) + j0 + t] = EPSV * (LOG_MU_NU - M - __logf(S));
    }
}

// ---------------- convergence check ----------------
__global__ void k_check(float* __restrict__ ws) {
    if (threadIdx.x == 0 && blockIdx.x == 0) {
        float e = ws[WS_ERR] * (1.0f / 8.0f);
        int* done = (int*)ws + WS_DONE;
        if (e < THRESHV) *done = 1;
        ws[WS_ERR] = 0.f;
    }
}

// ---------------- epilogue: pi, dis (uses exact fp32 C) ----------------
__global__ __launch_bounds__(256) void k_epi(float* __restrict__ out, const float* __restrict__ ws) {
    int b = blockIdx.z, jg = blockIdx.x, ic = blockIdx.y;
    int j = jg * 256 + threadIdx.x;
    int i0 = ic * 128;
    const float* u = ws + WS_U;
    const float* v = ws + WS_V;
    const float* C = out + OUT_C + ((size_t)b << 22);
    float* pi = out + OUT_PI + ((size_t)b << 22);
    float vj = v[(b << 11) + j];
    float accd = 0.f;
#pragma unroll 4
    for (int r = 0; r < 128; ++r) {
        int i = i0 + r;
        size_t idx = ((size_t)i << 11) + j;
        float cv = C[idx];
        float p = __expf((u[(b << 11) + i] + vj - cv) * INV_EPS);
        pi[idx] = p;
        accd = fmaf(p, cv, accd);
    }
    atomicAdd(out + OUT_DIS + (b << 11) + j, accd);
}

// ---------------- cost_b = sum_j dis_bj ----------------
__global__ void k_cost(float* __restrict__ out) {
    int b = blockIdx.x;
    float s = 0.f;
    for (int j = threadIdx.x; j < 2048; j += 256) s += out[OUT_DIS + (b << 11) + j];
#pragma unroll
    for (int off = 1; off < 64; off <<= 1) s += __shfl_xor(s, off);
    __shared__ float red[4];
    if ((threadIdx.x & 63) == 0) red[threadIdx.x >> 6] = s;
    __syncthreads();
    if (threadIdx.x == 0) out[OUT_COST + b] = red[0] + red[1] + red[2] + red[3];
}

extern "C" void kernel_launch(void* const* d_in, const int* in_sizes, int n_in,
                              void* d_out, int out_size, void* d_ws, size_t ws_size,
                              hipStream_t stream) {
    const float* x = (const float*)d_in[0];
    const float* y = (const float*)d_in[1];
    float* out = (float*)d_out;
    float* ws = (float*)d_ws;

    bool use16 = ws_size >= WS_C16_BYTE + C16_BYTES;
    _Float16* c16 = use16 ? (_Float16*)((char*)d_ws + WS_C16_BYTE) : nullptr;

    k_init<<<64, 256, 0, stream>>>(ws, out);
    k_sqnorm<<<2048, 256, 0, stream>>>(x, y, ws);
    k_gemm<<<dim3(32, 32, 8), 256, 0, stream>>>(x, y, ws, out, c16);
    for (int it = 0; it < MAX_ITER; ++it) {
        if (use16) {
            k_urow16<<<1024, 256, 0, stream>>>(c16, ws);
            k_vcol16<<<512, 256, 0, stream>>>(c16, ws);
        } else {
            k_urow<<<1024, 256, 0, stream>>>(out, ws);
            k_vcol<<<512, 256, 0, stream>>>(out, ws);
        }
        k_check<<<1, 64, 0, stream>>>(ws);
    }
    k_epi<<<dim3(8, 16, 8), 256, 0, stream>>>(out, ws);
    k_cost<<<8, 256, 0, stream>>>(out);
}